// Round 9
// baseline (245.285 us; speedup 1.0000x reference)
//
#include <hip/hip_runtime.h>
#include <stdint.h>

// DifferentiableSkeletonize on (2,1,256,256,256) binary fp32 mask.
// dilated = avgpool3(avgpool3(x)) -> separable 5-tap [1,2,3,2,1]/9 per axis
// (zero-extended); boundary planes (i=0,255) subtract one extra center tap.
// n = integer numerator in [0,729]; out = (x==0 && n>=9) ? 1.0f : 0.0f
// (threshold identity verified across all prior rounds, absmax 0).
//
// Round-9 structure: split at the COMPRESSION point.
//   K_pre : binarize + d-filter. Dependency-free grid-stride stream
//           (128 MiB fp32 in -> 32 MiB n_d|x bytes out). No barriers, no
//           marching window -> copy-like duty cycle.
//   K_main: w-filter + h-filter + threshold. Reads 32 MiB nd (L2/LLC
//           resident) + writes 128 MiB fp32 -> write-dominated (fills
//           prove pure writes run at 6.7 TB/s). 5x5 reg window marching
//           along w, no LDS, ~60 VGPR -> 8 waves/SIMD.
// All byte/SWAR formats identical to the verified two-phase kernels.

typedef float vfloat4 __attribute__((ext_vector_type(4)));

#define PRE_BLOCKS 2048   // 8192 waves * 16 cols = 131072 columns
#define CW 16             // w outputs per K_main wave
#define MAIN_BLOCKS 2048  // 512 slabs * 16 chunks / 4 waves

// d-axis filter: lane ln owns bytes for d = 4ln..4ln+3. b = 4 packed x-bits.
// wave_shr1 (0x138): lane i <- i-1 (lane0 -> 0)  == shfl_up(b,1)
// wave_shl1 (0x130): lane i <- i+1 (lane63 -> 0) == shfl_down(b,1)
__device__ __forceinline__ uint32_t row_pack(uint32_t b, const int ln) {
    uint32_t up = (uint32_t)__builtin_amdgcn_update_dpp(
        0, (int)b, 0x138, 0xf, 0xf, true);
    uint32_t dn = (uint32_t)__builtin_amdgcn_update_dpp(
        0, (int)b, 0x130, 0xf, 0xf, true);
    uint64_t W = (uint64_t)(up >> 16) | ((uint64_t)b << 16)
               | ((uint64_t)(dn & 0xffffu) << 48);
    uint64_t S = W + ((W >> 8) << 1) + (W >> 16) * 3u + ((W >> 24) << 1) + (W >> 32);
    uint32_t n = (uint32_t)S;
    if (ln == 0)  n -= (b & 0xffu);        // d==0 boundary correction
    if (ln == 63) n -= (b & 0xff000000u);  // d==255
    return n | (b << 7);                   // x-bit -> bit7 of each byte
}

__device__ __forceinline__ uint32_t bits_of(const vfloat4 v) {
    return (v.x > 0.5f ? 0x1u : 0u) | (v.y > 0.5f ? 0x100u : 0u)
         | (v.z > 0.5f ? 0x10000u : 0u) | (v.w > 0.5f ? 0x1000000u : 0u);
}

// K_pre: per column c = (bi*256+h)*256+w, nd[c*64+ln] = n_d bytes | x<<7.
// Pure stream: 16 cols/wave, 4 independent cols in flight.
__global__ __launch_bounds__(256) void skel_pre(const float* __restrict__ x,
                                                uint32_t* __restrict__ nd) {
    const int ln  = threadIdx.x & 63;
    const int wid = (blockIdx.x << 2) | (threadIdx.x >> 6);   // 0..8191
    const vfloat4* xv = (const vfloat4*)x;
    const uint32_t c0 = (uint32_t)wid * 16u;
    #pragma unroll
    for (int g = 0; g < 16; g += 4) {
        vfloat4 v[4];
        #pragma unroll
        for (int i = 0; i < 4; ++i)
            v[i] = xv[(c0 + (uint32_t)(g + i)) * 64u + (uint32_t)ln];
        #pragma unroll
        for (int i = 0; i < 4; ++i)
            nd[(c0 + (uint32_t)(g + i)) * 64u + (uint32_t)ln] =
                row_pack(bits_of(v[i]), ln);
    }
}

// K_main: wave owns (slab=(bi,hi), 16-w chunk); 5x5 nd window marching w.
// t[k] = w-filter of row hi-2+k (<=81/byte); h-SWAR over t -> threshold.
__global__ __launch_bounds__(256) void skel_main(const uint32_t* __restrict__ nd,
                                                 vfloat4* __restrict__ out) {
    const int ln  = threadIdx.x & 63;
    // chunked XCD swizzle (bijective: 2048 % 8 == 0): h-adjacent waves
    // (sharing nd rows) stay on one XCD's L2.
    const int bid = (int)((blockIdx.x & 7u) * (MAIN_BLOCKS / 8) + (blockIdx.x >> 3));
    const int wid = (bid << 2) | (threadIdx.x >> 6);          // 0..8191
    const int chunk = wid & 15;
    const int slab  = wid >> 4;            // bi*256 + hi, 0..511
    const int hi    = slab & 255, bi = slab >> 8;
    const int w0    = chunk * CW;

    uint32_t rowbase[5];                   // u32 index of nd row (bi,hk) at w=0
    uint32_t rmask[5];                     // all-ones if hk in range else 0
    #pragma unroll
    for (int k = 0; k < 5; ++k) {
        const int hk = hi - 2 + k;
        const int hc = hk < 0 ? 0 : (hk > 255 ? 255 : hk);
        rowbase[k] = ((uint32_t)bi * 256u + (uint32_t)hc) * 16384u + (uint32_t)ln;
        rmask[k]   = (hk >= 0 && hk <= 255) ? 0xffffffffu : 0u;
    }
    const bool hbnd = (hi == 0 || hi == 255);
    const uint32_t obase = (uint32_t)slab * 16384u + (uint32_t)ln;

    auto ldnd = [&](int k, int w) -> uint32_t {   // wave-uniform w mask
        if (w < 0 || w > 255) return 0u;
        return nd[rowbase[k] + (uint32_t)w * 64u];
    };

    uint32_t cur[5][5];
    #pragma unroll
    for (int k = 0; k < 5; ++k)
        #pragma unroll
        for (int i = 0; i < 5; ++i) cur[k][i] = ldnd(k, w0 - 2 + i);

    #pragma unroll
    for (int j = 0; j < CW; ++j) {
        const int w = w0 + j;
        uint32_t nxt[5];
        #pragma unroll
        for (int k = 0; k < 5; ++k) nxt[k] = ldnd(k, w + 3);  // next window col

        const uint32_t xb = cur[2][2];     // center x-bits (row hi, col w)
        uint32_t t[5];
        #pragma unroll
        for (int k = 0; k < 5; ++k) {      // w-filter, bytes <= 81
            const uint32_t m0 = cur[k][0] & 0x7f7f7f7fu,
                           m1 = cur[k][1] & 0x7f7f7f7fu,
                           m2 = cur[k][2] & 0x7f7f7f7fu,
                           m3 = cur[k][3] & 0x7f7f7f7fu,
                           m4 = cur[k][4] & 0x7f7f7f7fu;
            uint32_t s = m0 + (m1 << 1) + m2 * 3u + (m3 << 1) + m4;
            if (w == 0 || w == 255) s -= m2;        // w boundary correction
            t[k] = s & rmask[k];                    // zero OOB h rows
        }
        // h-SWAR (16-bit fields over even/odd bytes; max 729)
        const uint32_t e0 = t[0] & 0x00ff00ffu, e1 = t[1] & 0x00ff00ffu,
                       e2 = t[2] & 0x00ff00ffu, e3 = t[3] & 0x00ff00ffu,
                       e4 = t[4] & 0x00ff00ffu;
        const uint32_t o0 = (t[0] >> 8) & 0x00ff00ffu, o1 = (t[1] >> 8) & 0x00ff00ffu,
                       o2 = (t[2] >> 8) & 0x00ff00ffu, o3 = (t[3] >> 8) & 0x00ff00ffu,
                       o4 = (t[4] >> 8) & 0x00ff00ffu;
        uint32_t ae = e0 + (e1 << 1) + e2 * 3u + (e3 << 1) + e4;
        uint32_t ao = o0 + (o1 << 1) + o2 * 3u + (o3 << 1) + o4;
        if (hbnd) { ae -= e2; ao -= o2; }           // h boundary correction
        vfloat4 o;
        o.x = ((ae & 0xffffu) >= 9u && !((xb >> 7)  & 1u)) ? 1.0f : 0.0f;
        o.y = ((ao & 0xffffu) >= 9u && !((xb >> 15) & 1u)) ? 1.0f : 0.0f;
        o.z = ((ae >> 16)     >= 9u && !((xb >> 23) & 1u)) ? 1.0f : 0.0f;
        o.w = ((ao >> 16)     >= 9u && !((xb >> 31) & 1u)) ? 1.0f : 0.0f;
        __builtin_nontemporal_store(o, &out[obase + (uint32_t)w * 64u]);

        #pragma unroll
        for (int k = 0; k < 5; ++k) {
            cur[k][0] = cur[k][1]; cur[k][1] = cur[k][2];
            cur[k][2] = cur[k][3]; cur[k][3] = cur[k][4];
            cur[k][4] = nxt[k];
        }
    }
}

extern "C" void kernel_launch(void* const* d_in, const int* in_sizes, int n_in,
                              void* d_out, int out_size, void* d_ws, size_t ws_size,
                              hipStream_t stream) {
    const float* x = (const float*)d_in[0];
    uint32_t* nd = (uint32_t*)d_ws;            // 32 MiB scratch
    skel_pre<<<PRE_BLOCKS, 256, 0, stream>>>(x, nd);
    skel_main<<<MAIN_BLOCKS, 256, 0, stream>>>(nd, (vfloat4*)d_out);
}